// Round 3
// baseline (472.635 us; speedup 1.0000x reference)
//
#include <hip/hip_runtime.h>
#include <hip/hip_bf16.h>
#include <cmath>

#define NN 30000
#define KK 25
#define IN_F 64
#define FEAT 32
#define HH 128
#define OUTF 64
#define EE 480000

typedef __attribute__((ext_vector_type(8))) __bf16 bf16x8;
typedef __attribute__((ext_vector_type(16))) float f32x16;

__device__ inline float u2f(unsigned u) { return __builtin_bit_cast(float, u); }
__device__ inline unsigned short f2b(float f) {
    __bf16 h = (__bf16)f;
    return __builtin_bit_cast(unsigned short, h);
}
__device__ inline float blo(unsigned u) { return u2f(u << 16); }
__device__ inline float bhi(unsigned u) { return u2f(u & 0xffff0000u); }

// ---------------- K1: h0 = x @ w_pre + b_pre  (N,32) ----------------
__global__ void k_pre(const float* __restrict__ x, const float* __restrict__ w,
                      const float* __restrict__ b, float* __restrict__ h0) {
    int gid = blockIdx.x * 256 + threadIdx.x;
    if (gid >= NN * FEAT) return;
    int n = gid >> 5, c = gid & 31;
    const float* xr = x + n * IN_F;
    float acc = b[c];
#pragma unroll
    for (int j = 0; j < IN_F; ++j) acc = fmaf(xr[j], w[j * FEAT + c], acc);
    h0[gid] = acc;
}

// ---------------- K2: d1,d2 = dist MLPs (N*K each) ----------------
__global__ void k_dmlp(const float* __restrict__ dmax,
                       const float* __restrict__ w1a, const float* __restrict__ b1a,
                       const float* __restrict__ w2a, const float* __restrict__ b2a,
                       const float* __restrict__ w1b, const float* __restrict__ b1b,
                       const float* __restrict__ w2b, const float* __restrict__ b2b,
                       float* __restrict__ d1, float* __restrict__ d2) {
    int i = blockIdx.x * 256 + threadIdx.x;
    if (i >= NN * KK) return;
    float dm = dmax[i];
    float a1 = 0.f, a2 = 0.f;
#pragma unroll 8
    for (int h = 0; h < HH; ++h) {
        float t1 = fmaxf(fmaf(dm, w1a[h], b1a[h]), 0.f);
        a1 = fmaf(t1, w2a[h], a1);
        float t2 = fmaxf(fmaf(dm, w1b[h], b1b[h]), 0.f);
        a2 = fmaf(t2, w2b[h], a2);
    }
    d1[i] = a1 + b2a[0];
    d2[i] = a2 + b2b[0];
}

// ---------------- K3/K5: Gb = bf16(feat@wh[0:FIN]), S = feat@wh[FIN:2FIN] + bh ----------------
template <int FIN>
__global__ void k_gs_gemm(const float* __restrict__ feat, const float* __restrict__ wh,
                          const float* __restrict__ bh, unsigned short* __restrict__ Gb,
                          float* __restrict__ S) {
    __shared__ float ft[16][FIN + 4];
    int nb = blockIdx.x * 16;
    int t = threadIdx.x;
    for (int idx = t; idx < 16 * FIN; idx += 256) {
        int n = idx / FIN, j = idx % FIN;
        ft[n][j] = feat[(nb + n) * FIN + j];
    }
    __syncthreads();
    int h = t & 127, g = t >> 7;
    float accG[8], accS[8];
#pragma unroll
    for (int i = 0; i < 8; ++i) { accG[i] = 0.f; accS[i] = 0.f; }
#pragma unroll 4
    for (int j = 0; j < FIN; ++j) {
        float wA = wh[j * HH + h];
        float wB = wh[(FIN + j) * HH + h];
#pragma unroll
        for (int i = 0; i < 8; ++i) {
            float f = ft[g + 2 * i][j];
            accG[i] = fmaf(f, wA, accG[i]);
            accS[i] = fmaf(f, wB, accS[i]);
        }
    }
    float bias = bh[h];
#pragma unroll
    for (int i = 0; i < 8; ++i) {
        int n = nb + g + 2 * i;
        Gb[n * HH + h] = f2b(accG[i]);
        S[n * HH + h] = accS[i] + bias;
    }
}

// ---------------- K4: layer1 out_structure: h1 = mean_k relu(d1_k*G1[a_k] + S1) ----------------
// 4 nodes/block; 64 lanes per node; lane handles h = {2l, 2l+1} (uint = 2 bf16 gather).
__global__ void k_layer1(const unsigned* __restrict__ G1u, const float* __restrict__ S1,
                         const float* __restrict__ d1, const int* __restrict__ amax,
                         float* __restrict__ h1) {
    int t = threadIdx.x;
    int n = blockIdx.x * 4 + (t >> 6);
    int l = t & 63;
    float2 sv = *(const float2*)(S1 + n * HH + 2 * l);
    float acc0 = 0.f, acc1 = 0.f;
    const int* arow = amax + n * KK;
    const float* drow = d1 + n * KK;
#pragma unroll
    for (int k = 0; k < KK; ++k) {
        int a = arow[k];
        float dk = drow[k];
        unsigned g = G1u[a * 64 + l];
        acc0 += fmaxf(fmaf(dk, blo(g), sv.x), 0.f);
        acc1 += fmaxf(fmaf(dk, bhi(g), sv.y), 0.f);
    }
    float2 r;
    r.x = acc0 * (1.0f / 25.0f);
    r.y = acc1 * (1.0f / 25.0f);
    *(float2*)(h1 + n * HH + 2 * l) = r;
}

// ---------------- K6a: xpos[n,k] = sum_h relu(d2*G2[a]+S2)*wp + bp ----------------
// 1 node/block, 4 waves; wave w handles k = w, w+4, ...; S2 in regs.
__global__ void k_xpos(const unsigned* __restrict__ G2u, const float* __restrict__ S2,
                       const float* __restrict__ d2, const int* __restrict__ amax,
                       const float* __restrict__ wp, const float* __restrict__ bp,
                       float* __restrict__ xpos) {
    int t = threadIdx.x;
    int n = blockIdx.x;
    int w = t >> 6, l = t & 63;
    float2 sv = *(const float2*)(S2 + n * HH + 2 * l);
    float2 wpv = *(const float2*)(wp + 2 * l);
    float bpv = bp[0];
    const int* arow = amax + n * KK;
    const float* drow = d2 + n * KK;
    for (int k = w; k < KK; k += 4) {
        int a = arow[k];
        float dk = drow[k];
        unsigned g = G2u[a * 64 + l];
        float v = fmaxf(fmaf(dk, blo(g), sv.x), 0.f) * wpv.x +
                  fmaxf(fmaf(dk, bhi(g), sv.y), 0.f) * wpv.y;
        v += __shfl_xor(v, 1, 64);
        v += __shfl_xor(v, 2, 64);
        v += __shfl_xor(v, 4, 64);
        v += __shfl_xor(v, 8, 64);
        v += __shfl_xor(v, 16, 64);
        v += __shfl_xor(v, 32, 64);
        if (l == 0) xpos[n * KK + k] = v + bpv;
    }
}

// ---------------- K6b: hl = relu(relu(xpos)/nrm @ wlin + blin)  (N,128) ----------------
__global__ void k_hl(const float* __restrict__ xpos, const float* __restrict__ wlin,
                     const float* __restrict__ blin, float* __restrict__ hl) {
    __shared__ float xs[2][28];
    int t = threadIdx.x;
    int ln = t >> 7, h = t & 127;
    int n = blockIdx.x * 2 + ln;
    if (h < KK) xs[ln][h] = xpos[n * KK + h];
    __syncthreads();
    float ss = 0.f;
#pragma unroll
    for (int k = 0; k < KK; ++k) { float v = xs[ln][k]; ss = fmaf(v, v, ss); }
    float inv = 1.0f / fmaxf(sqrtf(ss), 1e-12f);
    float acc = blin[h];
#pragma unroll
    for (int k = 0; k < KK; ++k) {
        float v = fmaxf(xs[ln][k], 0.f) * inv;
        acc = fmaf(v, wlin[k * HH + h], acc);
    }
    hl[n * HH + h] = fmaxf(acc, 0.f);
}

// ---------------- K7: ab[n][0..511] = hl@W1top | hl@W1bot + ff_b1 (bf16 out) ----------------
__global__ void k_ab(const float* __restrict__ hl, const float* __restrict__ ffw1,
                     const float* __restrict__ ffb1, unsigned short* __restrict__ ab) {
    __shared__ float ht[16][132];
    int bc = blockIdx.x & 3;
    int nb = (blockIdx.x >> 2) * 16;
    int t = threadIdx.x;
    for (int idx = t; idx < 16 * HH; idx += 256) {
        int n = idx >> 7, j = idx & 127;
        ht[n][j] = hl[(nb + n) * HH + j];
    }
    __syncthreads();
    int c = t & 127, g = t >> 7;
    int c0 = bc * 128 + c;
    int rowoff = (c0 < 256) ? 0 : 128;
    int col = c0 & 255;
    float acc[8];
#pragma unroll
    for (int i = 0; i < 8; ++i) acc[i] = 0.f;
#pragma unroll 4
    for (int j = 0; j < HH; ++j) {
        float w = ffw1[(rowoff + j) * 256 + col];
#pragma unroll
        for (int i = 0; i < 8; ++i) acc[i] = fmaf(ht[g + 2 * i][j], w, acc[i]);
    }
    float bias = (c0 >= 256) ? ffb1[col] : 0.f;
#pragma unroll
    for (int i = 0; i < 8; ++i) {
        int n = nb + g + 2 * i;
        ab[n * 512 + c0] = f2b(acc[i] + bias);
    }
}

// ---------------- K7b: wt[c][k] = bf16(ff_w2[k][c])  (64x256 transposed) ----------------
__global__ void k_w2prep(const float* __restrict__ w2, unsigned short* __restrict__ wt) {
    int i = blockIdx.x * 256 + threadIdx.x;
    if (i >= 256 * 64) return;
    int k = i >> 6, c = i & 63;
    wt[c * 256 + k] = f2b(w2[i]);
}

// ---------------- K8: edges via MFMA ----------------
__global__ __launch_bounds__(256) void k_edge_mfma(
    const unsigned short* __restrict__ abf, const int* __restrict__ ei,
    const unsigned short* __restrict__ wtb, const float* __restrict__ ffb2,
    float* __restrict__ out) {
    int t = threadIdx.x;
    int l = t & 63;
    int eb = blockIdx.x * 128 + (t >> 6) * 32;
    int erow = l & 31;
    int khalf = (l >> 5) * 8;
    int e = eb + erow;
    int src = ei[e];
    int dst = ei[EE + e];
    const unsigned short* ap = abf + (size_t)src * 512;
    const unsigned short* bp = abf + (size_t)dst * 512 + 256;
    const unsigned short* w0 = wtb + erow * 256 + khalf;
    const unsigned short* w1 = w0 + 32 * 256;

    f32x16 acc0, acc1;
#pragma unroll
    for (int i = 0; i < 16; ++i) { acc0[i] = 0.f; acc1[i] = 0.f; }

#pragma unroll 4
    for (int kt = 0; kt < 16; ++kt) {
        int k0 = kt * 16 + khalf;
        uint4 av = *(const uint4*)(ap + k0);
        uint4 bv = *(const uint4*)(bp + k0);
        unsigned ua[4] = {av.x, av.y, av.z, av.w};
        unsigned ub[4] = {bv.x, bv.y, bv.z, bv.w};
        bf16x8 af;
#pragma unroll
        for (int q = 0; q < 4; ++q) {
            float a0 = blo(ua[q]), a1 = bhi(ua[q]);
            float b0 = blo(ub[q]), b1 = bhi(ub[q]);
            af[2 * q]     = (__bf16)fmaxf(a0 + b0, 0.f);
            af[2 * q + 1] = (__bf16)fmaxf(a1 + b1, 0.f);
        }
        bf16x8 bf0 = *(const bf16x8*)(w0 + kt * 16);
        bf16x8 bf1 = *(const bf16x8*)(w1 + kt * 16);
        acc0 = __builtin_amdgcn_mfma_f32_32x32x16_bf16(af, bf0, acc0, 0, 0, 0);
        acc1 = __builtin_amdgcn_mfma_f32_32x32x16_bf16(af, bf1, acc1, 0, 0, 0);
    }

    int col = erow;
    float bias0 = ffb2[col], bias1 = ffb2[col + 32];
    int rbase = 4 * (l >> 5);
#pragma unroll
    for (int r = 0; r < 16; ++r) {
        int row = (r & 3) + 8 * (r >> 2) + rbase;
        size_t o = (size_t)(eb + row) * 64;
        out[o + col] = acc0[r] + bias0;
        out[o + 32 + col] = acc1[r] + bias1;
    }
}

extern "C" void kernel_launch(void* const* d_in, const int* in_sizes, int n_in,
                              void* d_out, int out_size, void* d_ws, size_t ws_size,
                              hipStream_t stream) {
    const float* x     = (const float*)d_in[0];
    const float* dmax  = (const float*)d_in[1];
    const int*   amax  = (const int*)d_in[2];
    const int*   ei    = (const int*)d_in[3];
    const float* w_pre = (const float*)d_in[5];
    const float* b_pre = (const float*)d_in[6];
    const float* l1w1  = (const float*)d_in[7];
    const float* l1b1  = (const float*)d_in[8];
    const float* l1w2  = (const float*)d_in[9];
    const float* l1b2  = (const float*)d_in[10];
    const float* l1wh  = (const float*)d_in[11];
    const float* l1bh  = (const float*)d_in[12];
    const float* l2w1  = (const float*)d_in[15];
    const float* l2b1  = (const float*)d_in[16];
    const float* l2w2  = (const float*)d_in[17];
    const float* l2b2  = (const float*)d_in[18];
    const float* l2wh  = (const float*)d_in[19];
    const float* l2bh  = (const float*)d_in[20];
    const float* l2wp  = (const float*)d_in[21];
    const float* l2bp  = (const float*)d_in[22];
    const float* wlin  = (const float*)d_in[23];
    const float* blin  = (const float*)d_in[24];
    const float* ffw1  = (const float*)d_in[25];
    const float* ffb1  = (const float*)d_in[26];
    const float* ffw2  = (const float*)d_in[27];
    const float* ffb2  = (const float*)d_in[28];

    float* ws = (float*)d_ws;
    // Workspace layout (float offsets):
    //   d1@0 (.75M)  d2@.75M (.75M)  h0@1.5M (.96M)
    //   Gb(ushort)@2.5M (1.92M fl)  S@4.5M (3.84M fl)   [G1/S1 then reused for G2/S2]
    //   h1@8.5M (3.84M)  xpos@12.5M (.75M)  hl@13.5M (3.84M)  wt(ushort)@17.5M (8k fl)
    //   ab(ushort)@0 (7.68M fl) — overwrites d*/h0/Gb/S after k_xpos is done
    float* d1 = ws + 0;
    float* d2 = ws + 750000;
    float* h0 = ws + 1500000;
    unsigned short* Gb = (unsigned short*)(ws + 2500000);
    float* S  = ws + 4500000;
    float* h1 = ws + 8500000;
    float* xpos = ws + 12500000;
    float* hl = ws + 13500000;
    unsigned short* wt = (unsigned short*)(ws + 17500000);
    unsigned short* ab = (unsigned short*)ws;
    float* out = (float*)d_out;

    k_pre<<<(NN * FEAT + 255) / 256, 256, 0, stream>>>(x, w_pre, b_pre, h0);
    k_dmlp<<<(NN * KK + 255) / 256, 256, 0, stream>>>(dmax, l1w1, l1b1, l1w2, l1b2,
                                                      l2w1, l2b1, l2w2, l2b2, d1, d2);
    k_w2prep<<<64, 256, 0, stream>>>(ffw2, wt);
    k_gs_gemm<FEAT><<<NN / 16, 256, 0, stream>>>(h0, l1wh, l1bh, Gb, S);
    k_layer1<<<NN / 4, 256, 0, stream>>>((const unsigned*)Gb, S, d1, amax, h1);
    k_gs_gemm<HH><<<NN / 16, 256, 0, stream>>>(h1, l2wh, l2bh, Gb, S);
    k_xpos<<<NN, 256, 0, stream>>>((const unsigned*)Gb, S, d2, amax, l2wp, l2bp, xpos);
    k_hl<<<NN / 2, 256, 0, stream>>>(xpos, wlin, blin, hl);
    k_ab<<<(NN / 16) * 4, 256, 0, stream>>>(hl, ffw1, ffb1, ab);
    k_edge_mfma<<<EE / 128, 256, 0, stream>>>(ab, ei, wt, ffb2, out);
}

// Round 4
// 381.659 us; speedup vs baseline: 1.2384x; 1.2384x over previous
//
#include <hip/hip_runtime.h>
#include <hip/hip_bf16.h>
#include <cmath>

#define NN 30000
#define KK 25
#define IN_F 64
#define FEAT 32
#define HH 128
#define OUTF 64
#define EE 480000

typedef __attribute__((ext_vector_type(8))) __bf16 bf16x8;
typedef __attribute__((ext_vector_type(16))) float f32x16;

__device__ inline float u2f(unsigned u) { return __builtin_bit_cast(float, u); }
__device__ inline unsigned short f2b(float f) {
    __bf16 h = (__bf16)f;
    return __builtin_bit_cast(unsigned short, h);
}
__device__ inline float blo(unsigned u) { return u2f(u << 16); }
__device__ inline float bhi(unsigned u) { return u2f(u & 0xffff0000u); }

// ---------------- K2: d1,d2 = dist MLPs (N*K each) ----------------
__global__ void k_dmlp(const float* __restrict__ dmax,
                       const float* __restrict__ w1a, const float* __restrict__ b1a,
                       const float* __restrict__ w2a, const float* __restrict__ b2a,
                       const float* __restrict__ w1b, const float* __restrict__ b1b,
                       const float* __restrict__ w2b, const float* __restrict__ b2b,
                       float* __restrict__ d1, float* __restrict__ d2) {
    int i = blockIdx.x * 256 + threadIdx.x;
    if (i >= NN * KK) return;
    float dm = dmax[i];
    float a1 = 0.f, a2 = 0.f;
#pragma unroll 8
    for (int h = 0; h < HH; ++h) {
        float t1 = fmaxf(fmaf(dm, w1a[h], b1a[h]), 0.f);
        a1 = fmaf(t1, w2a[h], a1);
        float t2 = fmaxf(fmaf(dm, w1b[h], b1b[h]), 0.f);
        a2 = fmaf(t2, w2b[h], a2);
    }
    d1[i] = a1 + b2a[0];
    d2[i] = a2 + b2b[0];
}

// ---------------- K0: weight prep ----------------
// wfuse[j][h], j<64: (w_pre@whA)[j][h]; j>=64: (w_pre@whB)[j-64][h]
// bfuse[0..127]=b_pre@whA; [128..255]=b_pre@whB + l1bh
// wt[c][k] = bf16(ff_w2[k][c])
__global__ void k_wprep(const float* __restrict__ w_pre, const float* __restrict__ b_pre,
                        const float* __restrict__ l1wh, const float* __restrict__ l1bh,
                        const float* __restrict__ ffw2,
                        float* __restrict__ wfuse, float* __restrict__ bfuse,
                        unsigned short* __restrict__ wt) {
    int gid = blockIdx.x * 256 + threadIdx.x;
    if (gid < 128 * 128) {
        int j = gid >> 7, h = gid & 127;
        int half = j >> 6, jj = j & 63;
        const float* wrow = w_pre + jj * FEAT;
        const float* wh = l1wh + half * FEAT * HH + h;
        float acc = 0.f;
#pragma unroll
        for (int c = 0; c < FEAT; ++c) acc = fmaf(wrow[c], wh[c * HH], acc);
        wfuse[gid] = acc;
    } else if (gid < 128 * 128 + 256) {
        int r = gid - 128 * 128;
        int half = r >> 7, h = r & 127;
        const float* wh = l1wh + half * FEAT * HH + h;
        float acc = (half == 1) ? l1bh[h] : 0.f;
#pragma unroll
        for (int c = 0; c < FEAT; ++c) acc = fmaf(b_pre[c], wh[c * HH], acc);
        bfuse[r] = acc;
    } else if (gid < 128 * 128 + 256 + 256 * 64) {
        int i = gid - (128 * 128 + 256);
        int k = i >> 6, c = i & 63;
        wt[c * 256 + k] = f2b(ffw2[i]);
    }
}

// ---------------- K3/K5: Gb = bf16(feat@wh[0:FIN] + gb), S = feat@wh[FIN:] + sb ----------------
template <int FIN>
__global__ void k_gs_gemm(const float* __restrict__ feat, const float* __restrict__ wh,
                          const float* __restrict__ gb, const float* __restrict__ sb,
                          unsigned short* __restrict__ Gb, float* __restrict__ S) {
    __shared__ float ft[16][FIN + 4];
    int nb = blockIdx.x * 16;
    int t = threadIdx.x;
    for (int idx = t; idx < 16 * FIN; idx += 256) {
        int n = idx / FIN, j = idx % FIN;
        ft[n][j] = feat[(nb + n) * FIN + j];
    }
    __syncthreads();
    int h = t & 127, g = t >> 7;
    float accG[8], accS[8];
#pragma unroll
    for (int i = 0; i < 8; ++i) { accG[i] = 0.f; accS[i] = 0.f; }
#pragma unroll 4
    for (int j = 0; j < FIN; ++j) {
        float wA = wh[j * HH + h];
        float wB = wh[(FIN + j) * HH + h];
#pragma unroll
        for (int i = 0; i < 8; ++i) {
            float f = ft[g + 2 * i][j];
            accG[i] = fmaf(f, wA, accG[i]);
            accS[i] = fmaf(f, wB, accS[i]);
        }
    }
    float gbv = gb ? gb[h] : 0.f;
    float sbv = sb[h];
#pragma unroll
    for (int i = 0; i < 8; ++i) {
        int n = nb + g + 2 * i;
        Gb[n * HH + h] = f2b(accG[i] + gbv);
        S[n * HH + h] = accS[i] + sbv;
    }
}

// ---------------- K4: layer1: h1 = mean_k relu(d1_k*G1[a_k] + S1) ----------------
__global__ void k_layer1(const unsigned* __restrict__ G1u, const float* __restrict__ S1,
                         const float* __restrict__ d1, const int* __restrict__ amax,
                         float* __restrict__ h1) {
    int t = threadIdx.x;
    int n = blockIdx.x * 4 + (t >> 6);
    int l = t & 63;
    float2 sv = *(const float2*)(S1 + n * HH + 2 * l);
    float acc0 = 0.f, acc1 = 0.f;
    const int* arow = amax + n * KK;
    const float* drow = d1 + n * KK;
#pragma unroll
    for (int k = 0; k < KK; ++k) {
        int a = arow[k];
        float dk = drow[k];
        unsigned g = G1u[a * 64 + l];
        acc0 += fmaxf(fmaf(dk, blo(g), sv.x), 0.f);
        acc1 += fmaxf(fmaf(dk, bhi(g), sv.y), 0.f);
    }
    float2 r;
    r.x = acc0 * (1.0f / 25.0f);
    r.y = acc1 * (1.0f / 25.0f);
    *(float2*)(h1 + n * HH + 2 * l) = r;
}

// ---------------- K6: layer2 pos + norm + w_lin, fused: hl (N,128) ----------------
// 1 node/block, 4 waves. Wave w handles k = w+4j (7 for w=0, else 6): all 7
// gathers issued up-front, then 7 interleaved shuffle-reduce chains.
__global__ __launch_bounds__(256) void k_xpos2(
    const unsigned* __restrict__ G2u, const float* __restrict__ S2,
    const float* __restrict__ d2, const int* __restrict__ amax,
    const float* __restrict__ wp, const float* __restrict__ bp,
    const float* __restrict__ wlin, const float* __restrict__ blin,
    float* __restrict__ hl) {
    __shared__ float xs[28];
    int t = threadIdx.x;
    int n = blockIdx.x;
    int w = t >> 6, l = t & 63;
    float2 sv = *(const float2*)(S2 + n * HH + 2 * l);
    float2 wpv = *(const float2*)(wp + 2 * l);
    float bpv = bp[0];
    const int* arow = amax + n * KK;
    const float* drow = d2 + n * KK;
    int kcnt = (w == 0) ? 7 : 6;
    unsigned gv[7];
    float dk[7];
#pragma unroll
    for (int j = 0; j < 7; ++j) {
        if (j < kcnt) {
            int k = w + 4 * j;
            int a = arow[k];
            gv[j] = G2u[a * 64 + l];
            dk[j] = drow[k];
        }
    }
    float v[7];
#pragma unroll
    for (int j = 0; j < 7; ++j) {
        if (j < kcnt) {
            v[j] = fmaxf(fmaf(dk[j], blo(gv[j]), sv.x), 0.f) * wpv.x +
                   fmaxf(fmaf(dk[j], bhi(gv[j]), sv.y), 0.f) * wpv.y;
        }
    }
#pragma unroll
    for (int s = 1; s < 64; s <<= 1) {
#pragma unroll
        for (int j = 0; j < 7; ++j) {
            if (j < kcnt) v[j] += __shfl_xor(v[j], s, 64);
        }
    }
    if (l == 0) {
#pragma unroll
        for (int j = 0; j < 7; ++j) {
            if (j < kcnt) xs[w + 4 * j] = v[j] + bpv;
        }
    }
    __syncthreads();
    if (t < HH) {
        float ss = 0.f;
#pragma unroll
        for (int k = 0; k < KK; ++k) { float x = xs[k]; ss = fmaf(x, x, ss); }
        float inv = 1.0f / fmaxf(sqrtf(ss), 1e-12f);
        float acc = blin[t];
#pragma unroll
        for (int k = 0; k < KK; ++k) {
            float x = fmaxf(xs[k], 0.f) * inv;
            acc = fmaf(x, wlin[k * HH + t], acc);
        }
        hl[n * HH + t] = fmaxf(acc, 0.f);
    }
}

// ---------------- K7: ab[n][0..511] = hl@W1top | hl@W1bot + ff_b1 (bf16 out) ----------------
__global__ void k_ab(const float* __restrict__ hl, const float* __restrict__ ffw1,
                     const float* __restrict__ ffb1, unsigned short* __restrict__ ab) {
    __shared__ float ht[16][132];
    int bc = blockIdx.x & 3;
    int nb = (blockIdx.x >> 2) * 16;
    int t = threadIdx.x;
    for (int idx = t; idx < 16 * HH; idx += 256) {
        int n = idx >> 7, j = idx & 127;
        ht[n][j] = hl[(nb + n) * HH + j];
    }
    __syncthreads();
    int c = t & 127, g = t >> 7;
    int c0 = bc * 128 + c;
    int rowoff = (c0 < 256) ? 0 : 128;
    int col = c0 & 255;
    float acc[8];
#pragma unroll
    for (int i = 0; i < 8; ++i) acc[i] = 0.f;
#pragma unroll 4
    for (int j = 0; j < HH; ++j) {
        float w = ffw1[(rowoff + j) * 256 + col];
#pragma unroll
        for (int i = 0; i < 8; ++i) acc[i] = fmaf(ht[g + 2 * i][j], w, acc[i]);
    }
    float bias = (c0 >= 256) ? ffb1[col] : 0.f;
#pragma unroll
    for (int i = 0; i < 8; ++i) {
        int n = nb + g + 2 * i;
        ab[n * 512 + c0] = f2b(acc[i] + bias);
    }
}

// ---------------- K8: edges via MFMA (R2-measured-best form, unroll 2) ----------------
__global__ __launch_bounds__(256) void k_edge_mfma(
    const unsigned short* __restrict__ abf, const int* __restrict__ ei,
    const unsigned short* __restrict__ wtb, const float* __restrict__ ffb2,
    float* __restrict__ out) {
    int t = threadIdx.x;
    int l = t & 63;
    int eb = blockIdx.x * 128 + (t >> 6) * 32;
    int erow = l & 31;
    int khalf = (l >> 5) * 8;
    int e = eb + erow;
    int src = ei[e];
    int dst = ei[EE + e];
    const unsigned short* ap = abf + (size_t)src * 512;
    const unsigned short* bp = abf + (size_t)dst * 512 + 256;
    const unsigned short* w0 = wtb + erow * 256 + khalf;
    const unsigned short* w1 = w0 + 32 * 256;

    f32x16 acc0, acc1;
#pragma unroll
    for (int i = 0; i < 16; ++i) { acc0[i] = 0.f; acc1[i] = 0.f; }

#pragma unroll 2
    for (int kt = 0; kt < 16; ++kt) {
        int k0 = kt * 16 + khalf;
        uint4 av = *(const uint4*)(ap + k0);
        uint4 bv = *(const uint4*)(bp + k0);
        unsigned ua[4] = {av.x, av.y, av.z, av.w};
        unsigned ub[4] = {bv.x, bv.y, bv.z, bv.w};
        bf16x8 af;
#pragma unroll
        for (int q = 0; q < 4; ++q) {
            float a0 = blo(ua[q]), a1 = bhi(ua[q]);
            float b0 = blo(ub[q]), b1 = bhi(ub[q]);
            af[2 * q]     = (__bf16)fmaxf(a0 + b0, 0.f);
            af[2 * q + 1] = (__bf16)fmaxf(a1 + b1, 0.f);
        }
        bf16x8 bf0 = *(const bf16x8*)(w0 + kt * 16);
        bf16x8 bf1 = *(const bf16x8*)(w1 + kt * 16);
        acc0 = __builtin_amdgcn_mfma_f32_32x32x16_bf16(af, bf0, acc0, 0, 0, 0);
        acc1 = __builtin_amdgcn_mfma_f32_32x32x16_bf16(af, bf1, acc1, 0, 0, 0);
    }

    int col = erow;
    float bias0 = ffb2[col], bias1 = ffb2[col + 32];
    int rbase = 4 * (l >> 5);
#pragma unroll
    for (int r = 0; r < 16; ++r) {
        int row = (r & 3) + 8 * (r >> 2) + rbase;
        size_t o = (size_t)(eb + row) * 64;
        out[o + col] = acc0[r] + bias0;
        out[o + 32 + col] = acc1[r] + bias1;
    }
}

extern "C" void kernel_launch(void* const* d_in, const int* in_sizes, int n_in,
                              void* d_out, int out_size, void* d_ws, size_t ws_size,
                              hipStream_t stream) {
    const float* x     = (const float*)d_in[0];
    const float* dmax  = (const float*)d_in[1];
    const int*   amax  = (const int*)d_in[2];
    const int*   ei    = (const int*)d_in[3];
    const float* w_pre = (const float*)d_in[5];
    const float* b_pre = (const float*)d_in[6];
    const float* l1w1  = (const float*)d_in[7];
    const float* l1b1  = (const float*)d_in[8];
    const float* l1w2  = (const float*)d_in[9];
    const float* l1b2  = (const float*)d_in[10];
    const float* l1wh  = (const float*)d_in[11];
    const float* l1bh  = (const float*)d_in[12];
    const float* l2w1  = (const float*)d_in[15];
    const float* l2b1  = (const float*)d_in[16];
    const float* l2w2  = (const float*)d_in[17];
    const float* l2b2  = (const float*)d_in[18];
    const float* l2wh  = (const float*)d_in[19];
    const float* l2bh  = (const float*)d_in[20];
    const float* l2wp  = (const float*)d_in[21];
    const float* l2bp  = (const float*)d_in[22];
    const float* wlin  = (const float*)d_in[23];
    const float* blin  = (const float*)d_in[24];
    const float* ffw1  = (const float*)d_in[25];
    const float* ffb1  = (const float*)d_in[26];
    const float* ffw2  = (const float*)d_in[27];
    const float* ffb2  = (const float*)d_in[28];

    float* ws = (float*)d_ws;
    // Layout (float offsets):
    //   d1@0 (.75M)  d2@.75M (.75M)
    //   Gb(ushort)@1.5M (1.92M fl)  S@3.5M (3.84M fl)
    //   h1@7.5M (3.84M)  hl@11.5M (3.84M)
    //   wfuse@15.5M (16384)  bfuse@15.52M (256)  wt(ushort)@15.53M (8192 fl)
    //   ab(ushort)@0 (7.68M fl) — overlaps d1/d2/Gb/S/h1-prefix, all dead by k_ab
    float* d1 = ws + 0;
    float* d2 = ws + 750000;
    unsigned short* Gb = (unsigned short*)(ws + 1500000);
    float* S  = ws + 3500000;
    float* h1 = ws + 7500000;
    float* hl = ws + 11500000;
    float* wfuse = ws + 15500000;
    float* bfuse = ws + 15520000;
    unsigned short* wt = (unsigned short*)(ws + 15530000);
    unsigned short* ab = (unsigned short*)ws;
    float* out = (float*)d_out;

    k_dmlp<<<(NN * KK + 255) / 256, 256, 0, stream>>>(dmax, l1w1, l1b1, l1w2, l1b2,
                                                      l2w1, l2b1, l2w2, l2b2, d1, d2);
    k_wprep<<<129, 256, 0, stream>>>(w_pre, b_pre, l1wh, l1bh, ffw2, wfuse, bfuse, wt);
    k_gs_gemm<IN_F><<<NN / 16, 256, 0, stream>>>(x, wfuse, bfuse, bfuse + 128, Gb, S);
    k_layer1<<<NN / 4, 256, 0, stream>>>((const unsigned*)Gb, S, d1, amax, h1);
    k_gs_gemm<HH><<<NN / 16, 256, 0, stream>>>(h1, l2wh, nullptr, l2bh, Gb, S);
    k_xpos2<<<NN, 256, 0, stream>>>((const unsigned*)Gb, S, d2, amax, l2wp, l2bp,
                                    wlin, blin, hl);
    k_ab<<<(NN / 16) * 4, 256, 0, stream>>>(hl, ffw1, ffb1, ab);
    k_edge_mfma<<<EE / 128, 256, 0, stream>>>(ab, ei, wt, ffb2, out);
}